// Round 5
// baseline (772.840 us; speedup 1.0000x reference)
//
#include <hip/hip_runtime.h>
#include <math.h>

#define KNN 20
#define PPTS 1024
#define NCL 16

typedef _Float16 f16x8 __attribute__((ext_vector_type(8)));
typedef _Float16 f16x4 __attribute__((ext_vector_type(4)));
typedef float f32x4 __attribute__((ext_vector_type(4)));

__device__ __forceinline__ float lrelu(float x) { return x > 0.f ? x : 0.2f * x; }

// ---------------- gather: h0 fp32 + hf16 packed ----------------
__global__ void gather_kernel(const float4* __restrict__ feat,
                              const int* __restrict__ clusters,
                              float4* __restrict__ h0,
                              f16x4* __restrict__ hf) {
    int n = blockIdx.x * 256 + threadIdx.x;   // over NCL*PPTS*32 float4s
    int c4 = n & 31;
    int row = n >> 5;
    int src = clusters[row];
    float4 v = feat[(size_t)src * 32 + c4];
    h0[(size_t)row * 32 + c4] = v;
    f16x4 o;
    o[0] = (_Float16)v.x; o[1] = (_Float16)v.y; o[2] = (_Float16)v.z; o[3] = (_Float16)v.w;
    hf[(size_t)row * 32 + c4] = o;
}

// ---------------- f32 (strided) -> f16 (packed row-major), for W5 ----------------
__global__ void tof16_kernel(const float* __restrict__ src, int ldsrc, int lgC4,
                             f16x4* __restrict__ dst) {
    int n = blockIdx.x * 256 + threadIdx.x;
    int c4 = n & ((1 << lgC4) - 1);
    int row = n >> lgC4;
    float4 v = *(const float4*)&src[(size_t)row * ldsrc + c4 * 4];
    f16x4 o;
    o[0] = (_Float16)v.x; o[1] = (_Float16)v.y; o[2] = (_Float16)v.z; o[3] = (_Float16)v.w;
    dst[((size_t)row << lgC4) + c4] = o;
}

// ---------------- weight split+convert: wn = f16(W[:,:C]), wv = f16(W[:,C:] - W[:,:C]) ----------------
__global__ void wcvt_kernel(const float* __restrict__ W, int lgC4,
                            f16x4* __restrict__ wn, f16x4* __restrict__ wv) {
    int n = blockIdx.x * 256 + threadIdx.x;   // O * C/4 threads
    int c4 = n & ((1 << lgC4) - 1);
    int o = n >> lgC4;
    int C = 4 << lgC4;
    float4 a = *(const float4*)&W[(size_t)o * 2 * C + c4 * 4];
    float4 b = *(const float4*)&W[(size_t)o * 2 * C + C + c4 * 4];
    f16x4 on, ov;
    on[0] = (_Float16)a.x; on[1] = (_Float16)a.y; on[2] = (_Float16)a.z; on[3] = (_Float16)a.w;
    ov[0] = (_Float16)(b.x - a.x); ov[1] = (_Float16)(b.y - a.y);
    ov[2] = (_Float16)(b.z - a.z); ov[3] = (_Float16)(b.w - a.w);
    wn[n] = on; wv[n] = ov;
}

// ---------------- squared row norms (fp32 input) ----------------
__global__ void sq_kernel(const float* __restrict__ h, int ldh, int C,
                          float* __restrict__ sq) {
    int lane = threadIdx.x & 63;
    int wid  = threadIdx.x >> 6;
    int row  = blockIdx.x * 4 + wid;
    const float* hr = h + (size_t)row * ldh;
    float s = 0.f;
    for (int c = lane; c < C; c += 64) { float v = hr[c]; s += v * v; }
    #pragma unroll
    for (int off = 32; off; off >>= 1) s += __shfl_down(s, off);
    if (lane == 0) sq[row] = s;
}

// ---------------- fused gram + top-K ----------------
// block: 16 rows x 1024 cols of one cluster. Wave w computes cols w*256..+255 via MFMA,
// packs monotone u32 keys into LDS (row rotated by 2*row to break bank aliasing),
// then wave w extracts top-20 for rows w*4..w*4+3.
__global__ __launch_bounds__(256) void grampk_kernel(
    const _Float16* __restrict__ hf, int C,
    const float* __restrict__ sq, int* __restrict__ idx)
{
    __shared__ unsigned keys[16 * 1024];   // 64 KB
    const int b = blockIdx.y;
    const _Float16* hb = hf + (size_t)b * PPTS * C;
    const float* sqb = sq + b * PPTS;
    const int w = threadIdx.x >> 6;
    const int lane = threadIdx.x & 63;
    const int col16 = lane & 15, quad = lane >> 4;
    const int i0 = blockIdx.x * 16;
    const int j0 = w * 256;
    f32x4 acc[16] = {};
    for (int kk = 0; kk < C; kk += 32) {
        f16x8 a = *(const f16x8*)&hb[(size_t)(i0 + col16) * C + kk + quad * 8];
        #pragma unroll
        for (int t = 0; t < 16; t++) {
            f16x8 bf = *(const f16x8*)&hb[(size_t)(j0 + t * 16 + col16) * C + kk + quad * 8];
            acc[t] = __builtin_amdgcn_mfma_f32_16x16x32_f16(a, bf, acc[t], 0, 0, 0);
        }
    }
    float sqi[4];
    #pragma unroll
    for (int r = 0; r < 4; r++) sqi[r] = sqb[i0 + quad * 4 + r];
    #pragma unroll
    for (int t = 0; t < 16; t++) {
        int j = j0 + t * 16 + col16;
        float sqj = sqb[j];
        #pragma unroll
        for (int r = 0; r < 4; r++) {
            int row = quad * 4 + r;
            float val = 2.f * acc[t][r] - sqi[r] - sqj;
            unsigned u = __float_as_uint(val);
            unsigned key = (u & 0x80000000u) ? ~u : (u | 0x80000000u);
            keys[(row << 10) | ((j + 2 * row) & 1023)] = (key & 0xFFFFFC00u) | (unsigned)j;
        }
    }
    __syncthreads();
    for (int rr = 0; rr < 4; rr++) {
        int row = w * 4 + rr;
        unsigned v[16];
        #pragma unroll
        for (int s = 0; s < 16; s++) v[s] = keys[(row << 10) | (s * 64 + lane)];
        unsigned myout = 0;
        for (int kk = 0; kk < KNN; kk++) {
            unsigned m = v[0];
            #pragma unroll
            for (int s = 1; s < 16; s++) m = (v[s] > m) ? v[s] : m;
            #pragma unroll
            for (int off = 1; off < 64; off <<= 1) {
                unsigned o = (unsigned)__shfl_xor((int)m, off);
                m = (o > m) ? o : m;
            }
            unsigned j = m & 1023u;
            if (lane == kk) myout = j;
            int sj = __builtin_amdgcn_readfirstlane((int)j);
            int sp = (sj + 2 * row) & 1023;      // LDS position of winner
            int sslot = sp >> 6;
            bool is_lane = (lane == (sp & 63));
            #pragma unroll
            for (int s = 0; s < 16; s++)
                if (s == sslot) v[s] = is_lane ? 0u : v[s];
        }
        if (lane < KNN) idx[((size_t)b * PPTS + i0 + row) * KNN + lane] = (int)myout;
    }
}

// ---------------- U/V via f16 MFMA: U = H*Wn^T, V = H*(Wc-Wn)^T ----------------
__global__ __launch_bounds__(256) void uv_mfma_kernel(
    const _Float16* __restrict__ hf, int C, int O,
    const _Float16* __restrict__ wn, const _Float16* __restrict__ wv,
    float* __restrict__ U, float* __restrict__ V)
{
    const int w = threadIdx.x >> 6;
    const int lane = threadIdx.x & 63;
    const int col16 = lane & 15, quad = lane >> 4;
    const int r0 = blockIdx.y * 64 + w * 16;
    const int o0 = blockIdx.x * 64;
    f32x4 au[4] = {}, av[4] = {};
    for (int kk = 0; kk < C; kk += 32) {
        f16x8 a = *(const f16x8*)&hf[(size_t)(r0 + col16) * C + kk + quad * 8];
        #pragma unroll
        for (int t = 0; t < 4; t++) {
            f16x8 bn = *(const f16x8*)&wn[(size_t)(o0 + t * 16 + col16) * C + kk + quad * 8];
            au[t] = __builtin_amdgcn_mfma_f32_16x16x32_f16(a, bn, au[t], 0, 0, 0);
            f16x8 bv = *(const f16x8*)&wv[(size_t)(o0 + t * 16 + col16) * C + kk + quad * 8];
            av[t] = __builtin_amdgcn_mfma_f32_16x16x32_f16(a, bv, av[t], 0, 0, 0);
        }
    }
    #pragma unroll
    for (int t = 0; t < 4; t++) {
        int o = o0 + t * 16 + col16;
        #pragma unroll
        for (int r = 0; r < 4; r++) {
            int p = r0 + quad * 4 + r;
            U[(size_t)p * O + o] = au[t][r];
            V[(size_t)p * O + o] = av[t][r];
        }
    }
}

// ---------------- aggregate: x = lrelu(s*(max_k U[idx] + V) + b); f16 side-outputs ----------------
__global__ void agg_kernel(const float* __restrict__ U, const float* __restrict__ V,
                           const int* __restrict__ idx, int lgO,
                           const float* __restrict__ sc, const float* __restrict__ bi,
                           float* __restrict__ xout,
                           _Float16* __restrict__ hnext,        // packed [16K][O], may be null
                           _Float16* __restrict__ xcf) {        // stride-512 slice
    int n = blockIdx.x * 256 + threadIdx.x;
    int O = 1 << lgO;
    int o = n & (O - 1);
    int pr = n >> lgO;           // b*P+p
    int b = pr >> 10;
    const int* id = idx + (size_t)pr * KNN;
    float m = -INFINITY;
    #pragma unroll
    for (int k = 0; k < KNN; k++) {
        int j = id[k];
        float u = U[((size_t)(b * PPTS + j) << lgO) + o];
        m = fmaxf(m, u);
    }
    float val = lrelu((m + V[((size_t)pr << lgO) + o]) * sc[o] + bi[o]);
    xout[(size_t)pr * 512 + o] = val;
    _Float16 hv = (_Float16)val;
    if (hnext) hnext[((size_t)pr << lgO) + o] = hv;
    xcf[(size_t)pr * 512 + o] = hv;
}

// ---------------- fused conv5 + pool: partial max/sum per (cluster, chunk, o) ----------------
__global__ __launch_bounds__(256) void conv5pool_kernel(
    const _Float16* __restrict__ xcf, const _Float16* __restrict__ w5f,
    const float* __restrict__ s5, const float* __restrict__ b5,
    float* __restrict__ pmax, float* __restrict__ psum)
{
    __shared__ float lmax[4][64], lsum[4][64];
    const int w = threadIdx.x >> 6;
    const int lane = threadIdx.x & 63;
    const int col16 = lane & 15, quad = lane >> 4;
    const int p0 = blockIdx.x * 64 + w * 16;
    const int o0 = blockIdx.y * 64;
    f32x4 acc[4] = {};
    for (int kk = 0; kk < 512; kk += 32) {
        f16x8 a = *(const f16x8*)&xcf[(size_t)(p0 + col16) * 512 + kk + quad * 8];
        #pragma unroll
        for (int t = 0; t < 4; t++) {
            f16x8 bf = *(const f16x8*)&w5f[(size_t)(o0 + t * 16 + col16) * 512 + kk + quad * 8];
            acc[t] = __builtin_amdgcn_mfma_f32_16x16x32_f16(a, bf, acc[t], 0, 0, 0);
        }
    }
    #pragma unroll
    for (int t = 0; t < 4; t++) {
        int o = o0 + t * 16 + col16;
        float sc = s5[o], bi = b5[o];
        float vm = -INFINITY, vs = 0.f;
        #pragma unroll
        for (int r = 0; r < 4; r++) {
            float val = lrelu(acc[t][r] * sc + bi);
            vm = fmaxf(vm, val); vs += val;
        }
        #pragma unroll
        for (int off = 16; off < 64; off <<= 1) {
            vm = fmaxf(vm, __shfl_xor(vm, off));
            vs += __shfl_xor(vs, off);
        }
        if (quad == 0) { lmax[w][t * 16 + col16] = vm; lsum[w][t * 16 + col16] = vs; }
    }
    __syncthreads();
    if (threadIdx.x < 64) {
        int col = threadIdx.x;
        float m = lmax[0][col], s = lsum[0][col];
        #pragma unroll
        for (int q = 1; q < 4; q++) { m = fmaxf(m, lmax[q][col]); s += lsum[q][col]; }
        int cl = blockIdx.x >> 4, chunk = blockIdx.x & 15;
        size_t o = (size_t)(cl * 16 + chunk) * 512 + o0 + col;
        pmax[o] = m; psum[o] = s;
    }
}

// ---------------- pool reduce over 16 chunks ----------------
__global__ void poolred_kernel(const float* __restrict__ pmax, const float* __restrict__ psum,
                               float* __restrict__ feat) {
    int n = blockIdx.x * 256 + threadIdx.x;   // 16*512
    int o = n & 511, cl = n >> 9;
    float m = -INFINITY, s = 0.f;
    #pragma unroll
    for (int c = 0; c < 16; c++) {
        size_t q = (size_t)(cl * 16 + c) * 512 + o;
        m = fmaxf(m, pmax[q]); s += psum[q];
    }
    feat[(size_t)cl * 1024 + o] = m;
    feat[(size_t)cl * 1024 + 512 + o] = s * (1.f / 1024.f);
}

// ---------------- final MLP ----------------
__global__ void mlp1_kernel(const float* __restrict__ feat, const float* __restrict__ L1,
                            const float* __restrict__ s6, const float* __restrict__ b6,
                            float* __restrict__ z1) {
    int n = blockIdx.x * 256 + threadIdx.x;   // 16*512
    int o = n & 511, b = n >> 9;
    const float* f = feat + (size_t)b * 1024;
    const float* w = L1 + (size_t)o * 1024;
    float acc = 0.f;
    for (int c = 0; c < 1024; c++) acc = fmaf(f[c], w[c], acc);
    z1[n] = lrelu(acc * s6[o] + b6[o]);
}

__global__ void mlp2_kernel(const float* __restrict__ z1, const float* __restrict__ L2,
                            const float* __restrict__ bl2,
                            const float* __restrict__ s7, const float* __restrict__ b7,
                            float* __restrict__ z2) {
    int n = blockIdx.x * 256 + threadIdx.x;   // 16*256
    int o = n & 255, b = n >> 8;
    const float* f = z1 + (size_t)b * 512;
    const float* w = L2 + (size_t)o * 512;
    float acc = 0.f;
    for (int c = 0; c < 512; c++) acc = fmaf(f[c], w[c], acc);
    z2[n] = lrelu((acc + bl2[o]) * s7[o] + b7[o]);
}

__global__ void mlp3_kernel(const float* __restrict__ z2, const float* __restrict__ L3,
                            const float* __restrict__ bl3, float* __restrict__ out) {
    __shared__ float red[256];
    int t = threadIdx.x;
    int b = t >> 4, q = t & 15;
    float acc = 0.f;
    for (int c = q * 16; c < q * 16 + 16; c++) acc = fmaf(z2[(size_t)b * 256 + c], L3[c], acc);
    red[t] = acc;
    __syncthreads();
    if (q == 0) {
        float s = 0.f;
        #pragma unroll
        for (int i = 0; i < 16; i++) s += red[b * 16 + i];
        s += bl3[0];
        out[b] = 1.f / (1.f + expf(-s));
    }
}

extern "C" void kernel_launch(void* const* d_in, const int* in_sizes, int n_in,
                              void* d_out, int out_size, void* d_ws, size_t ws_size,
                              hipStream_t stream) {
    const float* features = (const float*)d_in[0];
    const int*   clusters = (const int*)d_in[1];
    const float* W1 = (const float*)d_in[2];
    const float* s1 = (const float*)d_in[3];
    const float* b1 = (const float*)d_in[4];
    const float* W2 = (const float*)d_in[5];
    const float* s2 = (const float*)d_in[6];
    const float* b2 = (const float*)d_in[7];
    const float* W3 = (const float*)d_in[8];
    const float* s3 = (const float*)d_in[9];
    const float* b3 = (const float*)d_in[10];
    const float* W4 = (const float*)d_in[11];
    const float* s4 = (const float*)d_in[12];
    const float* b4 = (const float*)d_in[13];
    const float* W5 = (const float*)d_in[14];
    const float* s5 = (const float*)d_in[15];
    const float* b5 = (const float*)d_in[16];
    const float* L1 = (const float*)d_in[17];
    const float* s6 = (const float*)d_in[18];
    const float* b6 = (const float*)d_in[19];
    const float* L2 = (const float*)d_in[20];
    const float* bl2 = (const float*)d_in[21];
    const float* s7 = (const float*)d_in[22];
    const float* b7 = (const float*)d_in[23];
    const float* L3 = (const float*)d_in[24];
    const float* bl3 = (const float*)d_in[25];

    float* ws = (float*)d_ws;
    // workspace layout (float units) — no pd buffer anymore
    float* h0  = ws;                                      // 2,097,152
    float* xc  = h0 + 2097152;                            // 8,388,608
    float* U   = xc + 8388608;                            // 4,194,304 (max O=256)
    float* V   = U + 4194304;                             // 4,194,304
    _Float16* xcf16 = (_Float16*)(V + 4194304);           // 8,388,608 halfs
    _Float16* w5f16 = xcf16 + 8388608;                    // 262,144 halfs
    _Float16* hf16  = w5f16 + 262144;                     // 2,097,152 halfs
    _Float16* wn16  = hf16 + 2097152;                     // 32,768 halfs
    _Float16* wv16  = wn16 + 32768;                       // 32,768 halfs
    int*   idx  = (int*)(wv16 + 32768);                   // 327,680 ints
    float* sq   = (float*)(idx + 327680);                 // 16,384
    float* pmax = sq + 16384;                             // 131,072
    float* psum = pmax + 131072;                          // 131,072
    float* feat = psum + 131072;                          // 16,384
    float* z1   = feat + 16384;                           // 8,192
    float* z2   = z1 + 8192;                              // 4,096

    gather_kernel<<<2048, 256, 0, stream>>>((const float4*)features, clusters,
                                            (float4*)h0, (f16x4*)hf16);

    auto stage = [&](const float* hin, int ldh, int C, int O, int lgO,
                     const float* W, const float* sc, const float* bi,
                     float* xout, _Float16* xcfslice, _Float16* hnext) {
        int lgC4 = (C == 128) ? 5 : 4;
        sq_kernel<<<4096, 256, 0, stream>>>(hin, ldh, C, sq);
        grampk_kernel<<<dim3(64, 16), 256, 0, stream>>>(hf16, C, sq, idx);
        wcvt_kernel<<<(O * (C / 4)) / 256, 256, 0, stream>>>(W, lgC4, (f16x4*)wn16, (f16x4*)wv16);
        uv_mfma_kernel<<<dim3(O / 64, 256), 256, 0, stream>>>(hf16, C, O, wn16, wv16, U, V);
        agg_kernel<<<(NCL * PPTS * O) / 256, 256, 0, stream>>>(U, V, idx, lgO, sc, bi,
                                                               xout, hnext, xcfslice);
    };

    stage(h0,       128, 128,  64, 6, W1, s1, b1, xc + 0,   xcf16 + 0,   hf16);
    stage(xc + 0,   512,  64,  64, 6, W2, s2, b2, xc + 64,  xcf16 + 64,  hf16);
    stage(xc + 64,  512,  64, 128, 7, W3, s3, b3, xc + 128, xcf16 + 128, hf16);
    stage(xc + 128, 512, 128, 256, 8, W4, s4, b4, xc + 256, xcf16 + 256, (_Float16*)nullptr);

    tof16_kernel<<<256, 256, 0, stream>>>(W5, 512, 7, (f16x4*)w5f16);
    conv5pool_kernel<<<dim3(256, 8), 256, 0, stream>>>(xcf16, w5f16, s5, b5, pmax, psum);
    poolred_kernel<<<32, 256, 0, stream>>>(pmax, psum, feat);
    mlp1_kernel<<<32, 256, 0, stream>>>(feat, L1, s6, b6, z1);
    mlp2_kernel<<<16, 256, 0, stream>>>(z1, L2, bl2, s7, b7, z2);
    mlp3_kernel<<<1, 256, 0, stream>>>(z2, L3, bl3, (float*)d_out);
}

// Round 6
// 585.950 us; speedup vs baseline: 1.3190x; 1.3190x over previous
//
#include <hip/hip_runtime.h>
#include <math.h>

#define KNN 20
#define PPTS 1024
#define NCL 16

typedef _Float16 f16x8 __attribute__((ext_vector_type(8)));
typedef _Float16 f16x4 __attribute__((ext_vector_type(4)));
typedef float f32x4 __attribute__((ext_vector_type(4)));

__device__ __forceinline__ float lrelu(float x) { return x > 0.f ? x : 0.2f * x; }

// ---------------- gather: h0 fp32 + hf16 packed ----------------
__global__ void gather_kernel(const float4* __restrict__ feat,
                              const int* __restrict__ clusters,
                              float4* __restrict__ h0,
                              f16x4* __restrict__ hf) {
    int n = blockIdx.x * 256 + threadIdx.x;   // over NCL*PPTS*32 float4s
    int c4 = n & 31;
    int row = n >> 5;
    int src = clusters[row];
    float4 v = feat[(size_t)src * 32 + c4];
    h0[(size_t)row * 32 + c4] = v;
    f16x4 o;
    o[0] = (_Float16)v.x; o[1] = (_Float16)v.y; o[2] = (_Float16)v.z; o[3] = (_Float16)v.w;
    hf[(size_t)row * 32 + c4] = o;
}

// ---------------- f32 (strided) -> f16 (packed row-major), for W5 ----------------
__global__ void tof16_kernel(const float* __restrict__ src, int ldsrc, int lgC4,
                             f16x4* __restrict__ dst) {
    int n = blockIdx.x * 256 + threadIdx.x;
    int c4 = n & ((1 << lgC4) - 1);
    int row = n >> lgC4;
    float4 v = *(const float4*)&src[(size_t)row * ldsrc + c4 * 4];
    f16x4 o;
    o[0] = (_Float16)v.x; o[1] = (_Float16)v.y; o[2] = (_Float16)v.z; o[3] = (_Float16)v.w;
    dst[((size_t)row << lgC4) + c4] = o;
}

// ---------------- weight split+convert: wn = f16(W[:,:C]), wv = f16(W[:,C:] - W[:,:C]) ----------------
__global__ void wcvt_kernel(const float* __restrict__ W, int lgC4,
                            f16x4* __restrict__ wn, f16x4* __restrict__ wv) {
    int n = blockIdx.x * 256 + threadIdx.x;   // O * C/4 threads
    int c4 = n & ((1 << lgC4) - 1);
    int o = n >> lgC4;
    int C = 4 << lgC4;
    float4 a = *(const float4*)&W[(size_t)o * 2 * C + c4 * 4];
    float4 b = *(const float4*)&W[(size_t)o * 2 * C + C + c4 * 4];
    f16x4 on, ov;
    on[0] = (_Float16)a.x; on[1] = (_Float16)a.y; on[2] = (_Float16)a.z; on[3] = (_Float16)a.w;
    ov[0] = (_Float16)(b.x - a.x); ov[1] = (_Float16)(b.y - a.y);
    ov[2] = (_Float16)(b.z - a.z); ov[3] = (_Float16)(b.w - a.w);
    wn[n] = on; wv[n] = ov;
}

// ---------------- squared row norms (fp32 input) ----------------
__global__ void sq_kernel(const float* __restrict__ h, int ldh, int C,
                          float* __restrict__ sq) {
    int lane = threadIdx.x & 63;
    int wid  = threadIdx.x >> 6;
    int row  = blockIdx.x * 4 + wid;
    const float* hr = h + (size_t)row * ldh;
    float s = 0.f;
    for (int c = lane; c < C; c += 64) { float v = hr[c]; s += v * v; }
    #pragma unroll
    for (int off = 32; off; off >>= 1) s += __shfl_down(s, off);
    if (lane == 0) sq[row] = s;
}

// ---------------- fused gram + top-K, 1024-thread blocks ----------------
// block: 16 rows x 1024 cols of one cluster, 16 waves. Wave w computes cols w*64..+63
// via MFMA (acc[4], low VGPR), packs monotone u32 keys into LDS (row rotated by 2*row
// to break write-phase bank aliasing), then wave w extracts top-20 for ONE row (= w).
__global__ __launch_bounds__(1024, 4) void grampk_kernel(
    const _Float16* __restrict__ hf, int C,
    const float* __restrict__ sq, int* __restrict__ idx)
{
    __shared__ unsigned keys[16 * 1024];   // 64 KB
    const int b = blockIdx.y;
    const _Float16* hb = hf + (size_t)b * PPTS * C;
    const float* sqb = sq + b * PPTS;
    const int w = threadIdx.x >> 6;          // 0..15
    const int lane = threadIdx.x & 63;
    const int col16 = lane & 15, quad = lane >> 4;
    const int i0 = blockIdx.x * 16;
    const int j0 = w * 64;
    f32x4 acc[4] = {};
    for (int kk = 0; kk < C; kk += 32) {
        f16x8 a = *(const f16x8*)&hb[(size_t)(i0 + col16) * C + kk + quad * 8];
        #pragma unroll
        for (int t = 0; t < 4; t++) {
            f16x8 bf = *(const f16x8*)&hb[(size_t)(j0 + t * 16 + col16) * C + kk + quad * 8];
            acc[t] = __builtin_amdgcn_mfma_f32_16x16x32_f16(a, bf, acc[t], 0, 0, 0);
        }
    }
    float sqi[4];
    #pragma unroll
    for (int r = 0; r < 4; r++) sqi[r] = sqb[i0 + quad * 4 + r];
    #pragma unroll
    for (int t = 0; t < 4; t++) {
        int j = j0 + t * 16 + col16;
        float sqj = sqb[j];
        #pragma unroll
        for (int r = 0; r < 4; r++) {
            int row = quad * 4 + r;
            float val = 2.f * acc[t][r] - sqi[r] - sqj;
            unsigned u = __float_as_uint(val);
            unsigned key = (u & 0x80000000u) ? ~u : (u | 0x80000000u);
            keys[(row << 10) | ((j + 2 * row) & 1023)] = (key & 0xFFFFFC00u) | (unsigned)j;
        }
    }
    __syncthreads();
    // extraction: wave w handles row w
    {
        const int row = w;
        unsigned v[16];
        #pragma unroll
        for (int s = 0; s < 16; s++) v[s] = keys[(row << 10) | (s * 64 + lane)];
        unsigned myout = 0;
        for (int kk = 0; kk < KNN; kk++) {
            unsigned m = v[0];
            #pragma unroll
            for (int s = 1; s < 16; s++) m = (v[s] > m) ? v[s] : m;
            #pragma unroll
            for (int off = 1; off < 64; off <<= 1) {
                unsigned o = (unsigned)__shfl_xor((int)m, off);
                m = (o > m) ? o : m;
            }
            unsigned j = m & 1023u;
            if (lane == kk) myout = j;
            int sj = __builtin_amdgcn_readfirstlane((int)j);
            int sp = (sj + 2 * row) & 1023;      // LDS position of winner
            int sslot = sp >> 6;
            bool is_lane = (lane == (sp & 63));
            #pragma unroll
            for (int s = 0; s < 16; s++)
                if (s == sslot) v[s] = is_lane ? 0u : v[s];
        }
        if (lane < KNN) idx[((size_t)b * PPTS + i0 + row) * KNN + lane] = (int)myout;
    }
}

// ---------------- U/V via f16 MFMA: U = H*Wn^T, V = H*(Wc-Wn)^T ----------------
__global__ __launch_bounds__(256) void uv_mfma_kernel(
    const _Float16* __restrict__ hf, int C, int O,
    const _Float16* __restrict__ wn, const _Float16* __restrict__ wv,
    float* __restrict__ U, float* __restrict__ V)
{
    const int w = threadIdx.x >> 6;
    const int lane = threadIdx.x & 63;
    const int col16 = lane & 15, quad = lane >> 4;
    const int r0 = blockIdx.y * 64 + w * 16;
    const int o0 = blockIdx.x * 64;
    f32x4 au[4] = {}, av[4] = {};
    for (int kk = 0; kk < C; kk += 32) {
        f16x8 a = *(const f16x8*)&hf[(size_t)(r0 + col16) * C + kk + quad * 8];
        #pragma unroll
        for (int t = 0; t < 4; t++) {
            f16x8 bn = *(const f16x8*)&wn[(size_t)(o0 + t * 16 + col16) * C + kk + quad * 8];
            au[t] = __builtin_amdgcn_mfma_f32_16x16x32_f16(a, bn, au[t], 0, 0, 0);
            f16x8 bv = *(const f16x8*)&wv[(size_t)(o0 + t * 16 + col16) * C + kk + quad * 8];
            av[t] = __builtin_amdgcn_mfma_f32_16x16x32_f16(a, bv, av[t], 0, 0, 0);
        }
    }
    #pragma unroll
    for (int t = 0; t < 4; t++) {
        int o = o0 + t * 16 + col16;
        #pragma unroll
        for (int r = 0; r < 4; r++) {
            int p = r0 + quad * 4 + r;
            U[(size_t)p * O + o] = au[t][r];
            V[(size_t)p * O + o] = av[t][r];
        }
    }
}

// ---------------- aggregate: x = lrelu(s*(max_k U[idx] + V) + b); f16 side-outputs ----------------
__global__ void agg_kernel(const float* __restrict__ U, const float* __restrict__ V,
                           const int* __restrict__ idx, int lgO,
                           const float* __restrict__ sc, const float* __restrict__ bi,
                           float* __restrict__ xout,
                           _Float16* __restrict__ hnext,        // packed [16K][O], may be null
                           _Float16* __restrict__ xcf) {        // stride-512 slice
    int n = blockIdx.x * 256 + threadIdx.x;
    int O = 1 << lgO;
    int o = n & (O - 1);
    int pr = n >> lgO;           // b*P+p
    int b = pr >> 10;
    const int* id = idx + (size_t)pr * KNN;
    float m = -INFINITY;
    #pragma unroll
    for (int k = 0; k < KNN; k++) {
        int j = id[k];
        float u = U[((size_t)(b * PPTS + j) << lgO) + o];
        m = fmaxf(m, u);
    }
    float val = lrelu((m + V[((size_t)pr << lgO) + o]) * sc[o] + bi[o]);
    xout[(size_t)pr * 512 + o] = val;
    _Float16 hv = (_Float16)val;
    if (hnext) hnext[((size_t)pr << lgO) + o] = hv;
    xcf[(size_t)pr * 512 + o] = hv;
}

// ---------------- fused conv5 + pool: 64p x 128o tile, partial max/sum ----------------
__global__ __launch_bounds__(256) void conv5pool_kernel(
    const _Float16* __restrict__ xcf, const _Float16* __restrict__ w5f,
    const float* __restrict__ s5, const float* __restrict__ b5,
    float* __restrict__ pmax, float* __restrict__ psum)
{
    __shared__ float lmax[4][128], lsum[4][128];
    const int w = threadIdx.x >> 6;
    const int lane = threadIdx.x & 63;
    const int col16 = lane & 15, quad = lane >> 4;
    const int p0 = blockIdx.x * 64 + w * 16;
    const int o0 = blockIdx.y * 128;
    f32x4 acc[8] = {};
    for (int kk = 0; kk < 512; kk += 32) {
        f16x8 a = *(const f16x8*)&xcf[(size_t)(p0 + col16) * 512 + kk + quad * 8];
        #pragma unroll
        for (int t = 0; t < 8; t++) {
            f16x8 bf = *(const f16x8*)&w5f[(size_t)(o0 + t * 16 + col16) * 512 + kk + quad * 8];
            acc[t] = __builtin_amdgcn_mfma_f32_16x16x32_f16(a, bf, acc[t], 0, 0, 0);
        }
    }
    #pragma unroll
    for (int t = 0; t < 8; t++) {
        int o = o0 + t * 16 + col16;
        float sc = s5[o], bi = b5[o];
        float vm = -INFINITY, vs = 0.f;
        #pragma unroll
        for (int r = 0; r < 4; r++) {
            float val = lrelu(acc[t][r] * sc + bi);
            vm = fmaxf(vm, val); vs += val;
        }
        #pragma unroll
        for (int off = 16; off < 64; off <<= 1) {
            vm = fmaxf(vm, __shfl_xor(vm, off));
            vs += __shfl_xor(vs, off);
        }
        if (quad == 0) { lmax[w][t * 16 + col16] = vm; lsum[w][t * 16 + col16] = vs; }
    }
    __syncthreads();
    if (threadIdx.x < 128) {
        int col = threadIdx.x;
        float m = lmax[0][col], s = lsum[0][col];
        #pragma unroll
        for (int q = 1; q < 4; q++) { m = fmaxf(m, lmax[q][col]); s += lsum[q][col]; }
        int cl = blockIdx.x >> 4, chunk = blockIdx.x & 15;
        size_t o = (size_t)(cl * 16 + chunk) * 512 + o0 + col;
        pmax[o] = m; psum[o] = s;
    }
}

// ---------------- pool reduce over 16 chunks ----------------
__global__ void poolred_kernel(const float* __restrict__ pmax, const float* __restrict__ psum,
                               float* __restrict__ feat) {
    int n = blockIdx.x * 256 + threadIdx.x;   // 16*512
    int o = n & 511, cl = n >> 9;
    float m = -INFINITY, s = 0.f;
    #pragma unroll
    for (int c = 0; c < 16; c++) {
        size_t q = (size_t)(cl * 16 + c) * 512 + o;
        m = fmaxf(m, pmax[q]); s += psum[q];
    }
    feat[(size_t)cl * 1024 + o] = m;
    feat[(size_t)cl * 1024 + 512 + o] = s * (1.f / 1024.f);
}

// ---------------- final MLP ----------------
__global__ void mlp1_kernel(const float* __restrict__ feat, const float* __restrict__ L1,
                            const float* __restrict__ s6, const float* __restrict__ b6,
                            float* __restrict__ z1) {
    int n = blockIdx.x * 256 + threadIdx.x;   // 16*512
    int o = n & 511, b = n >> 9;
    const float* f = feat + (size_t)b * 1024;
    const float* w = L1 + (size_t)o * 1024;
    float acc = 0.f;
    for (int c = 0; c < 1024; c++) acc = fmaf(f[c], w[c], acc);
    z1[n] = lrelu(acc * s6[o] + b6[o]);
}

__global__ void mlp2_kernel(const float* __restrict__ z1, const float* __restrict__ L2,
                            const float* __restrict__ bl2,
                            const float* __restrict__ s7, const float* __restrict__ b7,
                            float* __restrict__ z2) {
    int n = blockIdx.x * 256 + threadIdx.x;   // 16*256
    int o = n & 255, b = n >> 8;
    const float* f = z1 + (size_t)b * 512;
    const float* w = L2 + (size_t)o * 512;
    float acc = 0.f;
    for (int c = 0; c < 512; c++) acc = fmaf(f[c], w[c], acc);
    z2[n] = lrelu((acc + bl2[o]) * s7[o] + b7[o]);
}

__global__ void mlp3_kernel(const float* __restrict__ z2, const float* __restrict__ L3,
                            const float* __restrict__ bl3, float* __restrict__ out) {
    __shared__ float red[256];
    int t = threadIdx.x;
    int b = t >> 4, q = t & 15;
    float acc = 0.f;
    for (int c = q * 16; c < q * 16 + 16; c++) acc = fmaf(z2[(size_t)b * 256 + c], L3[c], acc);
    red[t] = acc;
    __syncthreads();
    if (q == 0) {
        float s = 0.f;
        #pragma unroll
        for (int i = 0; i < 16; i++) s += red[b * 16 + i];
        s += bl3[0];
        out[b] = 1.f / (1.f + expf(-s));
    }
}

extern "C" void kernel_launch(void* const* d_in, const int* in_sizes, int n_in,
                              void* d_out, int out_size, void* d_ws, size_t ws_size,
                              hipStream_t stream) {
    const float* features = (const float*)d_in[0];
    const int*   clusters = (const int*)d_in[1];
    const float* W1 = (const float*)d_in[2];
    const float* s1 = (const float*)d_in[3];
    const float* b1 = (const float*)d_in[4];
    const float* W2 = (const float*)d_in[5];
    const float* s2 = (const float*)d_in[6];
    const float* b2 = (const float*)d_in[7];
    const float* W3 = (const float*)d_in[8];
    const float* s3 = (const float*)d_in[9];
    const float* b3 = (const float*)d_in[10];
    const float* W4 = (const float*)d_in[11];
    const float* s4 = (const float*)d_in[12];
    const float* b4 = (const float*)d_in[13];
    const float* W5 = (const float*)d_in[14];
    const float* s5 = (const float*)d_in[15];
    const float* b5 = (const float*)d_in[16];
    const float* L1 = (const float*)d_in[17];
    const float* s6 = (const float*)d_in[18];
    const float* b6 = (const float*)d_in[19];
    const float* L2 = (const float*)d_in[20];
    const float* bl2 = (const float*)d_in[21];
    const float* s7 = (const float*)d_in[22];
    const float* b7 = (const float*)d_in[23];
    const float* L3 = (const float*)d_in[24];
    const float* bl3 = (const float*)d_in[25];

    float* ws = (float*)d_ws;
    // workspace layout (float units) — no pd buffer
    float* h0  = ws;                                      // 2,097,152
    float* xc  = h0 + 2097152;                            // 8,388,608
    float* U   = xc + 8388608;                            // 4,194,304 (max O=256)
    float* V   = U + 4194304;                             // 4,194,304
    _Float16* xcf16 = (_Float16*)(V + 4194304);           // 8,388,608 halfs
    _Float16* w5f16 = xcf16 + 8388608;                    // 262,144 halfs
    _Float16* hf16  = w5f16 + 262144;                     // 2,097,152 halfs
    _Float16* wn16  = hf16 + 2097152;                     // 32,768 halfs
    _Float16* wv16  = wn16 + 32768;                       // 32,768 halfs
    int*   idx  = (int*)(wv16 + 32768);                   // 327,680 ints
    float* sq   = (float*)(idx + 327680);                 // 16,384
    float* pmax = sq + 16384;                             // 131,072
    float* psum = pmax + 131072;                          // 131,072
    float* feat = psum + 131072;                          // 16,384
    float* z1   = feat + 16384;                           // 8,192
    float* z2   = z1 + 8192;                              // 4,096

    gather_kernel<<<2048, 256, 0, stream>>>((const float4*)features, clusters,
                                            (float4*)h0, (f16x4*)hf16);

    auto stage = [&](const float* hin, int ldh, int C, int O, int lgO,
                     const float* W, const float* sc, const float* bi,
                     float* xout, _Float16* xcfslice, _Float16* hnext) {
        int lgC4 = (C == 128) ? 5 : 4;
        sq_kernel<<<4096, 256, 0, stream>>>(hin, ldh, C, sq);
        grampk_kernel<<<dim3(64, 16), 1024, 0, stream>>>(hf16, C, sq, idx);
        wcvt_kernel<<<(O * (C / 4)) / 256, 256, 0, stream>>>(W, lgC4, (f16x4*)wn16, (f16x4*)wv16);
        uv_mfma_kernel<<<dim3(O / 64, 256), 256, 0, stream>>>(hf16, C, O, wn16, wv16, U, V);
        agg_kernel<<<(NCL * PPTS * O) / 256, 256, 0, stream>>>(U, V, idx, lgO, sc, bi,
                                                               xout, hnext, xcfslice);
    };

    stage(h0,       128, 128,  64, 6, W1, s1, b1, xc + 0,   xcf16 + 0,   hf16);
    stage(xc + 0,   512,  64,  64, 6, W2, s2, b2, xc + 64,  xcf16 + 64,  hf16);
    stage(xc + 64,  512,  64, 128, 7, W3, s3, b3, xc + 128, xcf16 + 128, hf16);
    stage(xc + 128, 512, 128, 256, 8, W4, s4, b4, xc + 256, xcf16 + 256, (_Float16*)nullptr);

    tof16_kernel<<<256, 256, 0, stream>>>(W5, 512, 7, (f16x4*)w5f16);
    conv5pool_kernel<<<dim3(256, 4), 256, 0, stream>>>(xcf16, w5f16, s5, b5, pmax, psum);
    poolred_kernel<<<32, 256, 0, stream>>>(pmax, psum, feat);
    mlp1_kernel<<<32, 256, 0, stream>>>(feat, L1, s6, b6, z1);
    mlp2_kernel<<<16, 256, 0, stream>>>(z1, L2, bl2, s7, b7, z2);
    mlp3_kernel<<<1, 256, 0, stream>>>(z2, L3, bl3, (float*)d_out);
}

// Round 7
// 503.539 us; speedup vs baseline: 1.5348x; 1.1637x over previous
//
#include <hip/hip_runtime.h>
#include <math.h>

#define KNN 20
#define PPTS 1024
#define NCL 16

typedef _Float16 f16x8 __attribute__((ext_vector_type(8)));
typedef _Float16 f16x4 __attribute__((ext_vector_type(4)));
typedef float f32x4 __attribute__((ext_vector_type(4)));

__device__ __forceinline__ float lrelu(float x) { return x > 0.f ? x : 0.2f * x; }

// Fragment-tiled f16 layout: 16-row x 32-col tiles, row-major within tile.
// half-index(row, k, K) = (row>>4)*16*K + (k>>5)*512 + (row&15)*32 + (k&31)
// A wave's MFMA fragment load (lane = col16 + 16*quad reads [row=col16][k=kchunk*32+quad*8..+8])
// covers ONE contiguous 1KB block -> fully coalesced.

// ---------------- gather: h0 fp32 row-major + hf16 tiled (K=128) ----------------
__global__ void gather_kernel(const float4* __restrict__ feat,
                              const int* __restrict__ clusters,
                              float4* __restrict__ h0,
                              f16x4* __restrict__ hf) {
    int n = blockIdx.x * 256 + threadIdx.x;   // over NCL*PPTS*32 float4s
    int c4 = n & 31;                           // k = c4*4, K=128
    int row = n >> 5;
    int src = clusters[row];
    float4 v = feat[(size_t)src * 32 + c4];
    h0[(size_t)row * 32 + c4] = v;
    f16x4 o;
    o[0] = (_Float16)v.x; o[1] = (_Float16)v.y; o[2] = (_Float16)v.z; o[3] = (_Float16)v.w;
    hf[(size_t)(row >> 4) * 512 + (c4 >> 3) * 128 + (row & 15) * 8 + (c4 & 7)] = o;
}

// ---------------- W5 f32 row-major -> f16 tiled (K=512) ----------------
__global__ void tof16_tiled_kernel(const float* __restrict__ src,
                                   f16x4* __restrict__ dst) {
    int n = blockIdx.x * 256 + threadIdx.x;    // rows*128 threads
    int c4 = n & 127;
    int row = n >> 7;
    float4 v = *(const float4*)&src[(size_t)row * 512 + c4 * 4];
    f16x4 o;
    o[0] = (_Float16)v.x; o[1] = (_Float16)v.y; o[2] = (_Float16)v.z; o[3] = (_Float16)v.w;
    dst[(size_t)(row >> 4) * 2048 + (c4 >> 3) * 128 + (row & 15) * 8 + (c4 & 7)] = o;
}

// ---------------- weight split+convert (tiled, K=C): wn = f16(W[:,:C]), wv = f16(W[:,C:]-W[:,:C]) ----------------
__global__ void wcvt_kernel(const float* __restrict__ W, int lgC4,
                            f16x4* __restrict__ wn, f16x4* __restrict__ wv) {
    int n = blockIdx.x * 256 + threadIdx.x;   // O * C/4 threads
    int c4 = n & ((1 << lgC4) - 1);
    int o = n >> lgC4;
    int C = 4 << lgC4;
    float4 a = *(const float4*)&W[(size_t)o * 2 * C + c4 * 4];
    float4 b = *(const float4*)&W[(size_t)o * 2 * C + C + c4 * 4];
    f16x4 on, ov;
    on[0] = (_Float16)a.x; on[1] = (_Float16)a.y; on[2] = (_Float16)a.z; on[3] = (_Float16)a.w;
    ov[0] = (_Float16)(b.x - a.x); ov[1] = (_Float16)(b.y - a.y);
    ov[2] = (_Float16)(b.z - a.z); ov[3] = (_Float16)(b.w - a.w);
    size_t ti = (size_t)(o >> 4) * (C * 4) + (c4 >> 3) * 128 + (o & 15) * 8 + (c4 & 7);
    wn[ti] = on; wv[ti] = ov;
}

// ---------------- squared row norms (fp32 input) ----------------
__global__ void sq_kernel(const float* __restrict__ h, int ldh, int C,
                          float* __restrict__ sq) {
    int lane = threadIdx.x & 63;
    int wid  = threadIdx.x >> 6;
    int row  = blockIdx.x * 4 + wid;
    const float* hr = h + (size_t)row * ldh;
    float s = 0.f;
    for (int c = lane; c < C; c += 64) { float v = hr[c]; s += v * v; }
    #pragma unroll
    for (int off = 32; off; off >>= 1) s += __shfl_down(s, off);
    if (lane == 0) sq[row] = s;
}

// ---------------- fused gram + top-K, 1024-thread blocks, tiled hf ----------------
template<int C>
__global__ __launch_bounds__(1024, 4) void grampk_kernel(
    const _Float16* __restrict__ hf,
    const float* __restrict__ sq, int* __restrict__ idx)
{
    __shared__ unsigned keys[16 * 1024];   // 64 KB
    const int b = blockIdx.y;
    const _Float16* hb = hf + (size_t)b * PPTS * C;
    const float* sqb = sq + b * PPTS;
    const int w = threadIdx.x >> 6;          // 0..15
    const int lane = threadIdx.x & 63;
    const int col16 = lane & 15, quad = lane >> 4;
    const int i0 = blockIdx.x * 16;
    const int j0 = w * 64;
    const _Float16* aB = hb + (size_t)blockIdx.x * 16 * C + col16 * 32 + quad * 8;
    const _Float16* bB = hb + (size_t)(w * 4) * 16 * C + col16 * 32 + quad * 8;
    f32x4 acc[4] = {};
    #pragma unroll
    for (int kc = 0; kc < C / 32; kc++) {
        f16x8 a = *(const f16x8*)&aB[kc * 512];
        #pragma unroll
        for (int t = 0; t < 4; t++) {
            f16x8 bf = *(const f16x8*)&bB[(size_t)t * 16 * C + kc * 512];
            acc[t] = __builtin_amdgcn_mfma_f32_16x16x32_f16(a, bf, acc[t], 0, 0, 0);
        }
    }
    float sqi[4];
    #pragma unroll
    for (int r = 0; r < 4; r++) sqi[r] = sqb[i0 + quad * 4 + r];
    #pragma unroll
    for (int t = 0; t < 4; t++) {
        int j = j0 + t * 16 + col16;
        float sqj = sqb[j];
        #pragma unroll
        for (int r = 0; r < 4; r++) {
            int row = quad * 4 + r;
            float val = 2.f * acc[t][r] - sqi[r] - sqj;
            unsigned u = __float_as_uint(val);
            unsigned key = (u & 0x80000000u) ? ~u : (u | 0x80000000u);
            keys[(row << 10) | ((j + 2 * row) & 1023)] = (key & 0xFFFFFC00u) | (unsigned)j;
        }
    }
    __syncthreads();
    // extraction: wave w handles row w
    {
        const int row = w;
        unsigned v[16];
        #pragma unroll
        for (int s = 0; s < 16; s++) v[s] = keys[(row << 10) | (s * 64 + lane)];
        unsigned myout = 0;
        for (int kk = 0; kk < KNN; kk++) {
            unsigned m = v[0];
            #pragma unroll
            for (int s = 1; s < 16; s++) m = (v[s] > m) ? v[s] : m;
            #pragma unroll
            for (int off = 1; off < 64; off <<= 1) {
                unsigned o = (unsigned)__shfl_xor((int)m, off);
                m = (o > m) ? o : m;
            }
            unsigned j = m & 1023u;
            if (lane == kk) myout = j;
            int sj = __builtin_amdgcn_readfirstlane((int)j);
            int sp = (sj + 2 * row) & 1023;      // LDS position of winner
            int sslot = sp >> 6;
            bool is_lane = (lane == (sp & 63));
            #pragma unroll
            for (int s = 0; s < 16; s++)
                if (s == sslot) v[s] = is_lane ? 0u : v[s];
        }
        if (lane < KNN) idx[((size_t)b * PPTS + i0 + row) * KNN + lane] = (int)myout;
    }
}

// ---------------- U/V via f16 MFMA, tiled inputs: U = H*Wn^T, V = H*(Wc-Wn)^T ----------------
template<int C>
__global__ __launch_bounds__(256, 4) void uv_mfma_kernel(
    const _Float16* __restrict__ hf, int O,
    const _Float16* __restrict__ wn, const _Float16* __restrict__ wv,
    float* __restrict__ U, float* __restrict__ V)
{
    const int w = threadIdx.x >> 6;
    const int lane = threadIdx.x & 63;
    const int col16 = lane & 15, quad = lane >> 4;
    const int r0 = blockIdx.y * 64 + w * 16;
    const int o0 = blockIdx.x * 64;
    const _Float16* aB = hf + (size_t)(r0 >> 4) * 16 * C + col16 * 32 + quad * 8;
    const _Float16* nB = wn + (size_t)(o0 >> 4) * 16 * C + col16 * 32 + quad * 8;
    const _Float16* vB = wv + (size_t)(o0 >> 4) * 16 * C + col16 * 32 + quad * 8;
    f32x4 au[4] = {}, av[4] = {};
    #pragma unroll
    for (int kc = 0; kc < C / 32; kc++) {
        f16x8 a = *(const f16x8*)&aB[kc * 512];
        #pragma unroll
        for (int t = 0; t < 4; t++) {
            f16x8 bn = *(const f16x8*)&nB[(size_t)t * 16 * C + kc * 512];
            au[t] = __builtin_amdgcn_mfma_f32_16x16x32_f16(a, bn, au[t], 0, 0, 0);
            f16x8 bv = *(const f16x8*)&vB[(size_t)t * 16 * C + kc * 512];
            av[t] = __builtin_amdgcn_mfma_f32_16x16x32_f16(a, bv, av[t], 0, 0, 0);
        }
    }
    #pragma unroll
    for (int t = 0; t < 4; t++) {
        int o = o0 + t * 16 + col16;
        #pragma unroll
        for (int r = 0; r < 4; r++) {
            int p = r0 + quad * 4 + r;
            U[(size_t)p * O + o] = au[t][r];
            V[(size_t)p * O + o] = av[t][r];
        }
    }
}

// ---------------- aggregate: x = lrelu(s*(max_k U[idx] + V) + b); tiled f16 side-outputs ----------------
__global__ void agg_kernel(const float* __restrict__ U, const float* __restrict__ V,
                           const int* __restrict__ idx, int lgO,
                           const float* __restrict__ sc, const float* __restrict__ bi,
                           float* __restrict__ xout,
                           _Float16* __restrict__ hnext,        // tiled [16K rows][O], may be null
                           _Float16* __restrict__ xcf, int co)  // tiled [16K rows][512], col offset
{
    int n = blockIdx.x * 256 + threadIdx.x;
    int O = 1 << lgO;
    int o = n & (O - 1);
    int pr = n >> lgO;           // b*P+p
    int b = pr >> 10;
    const int* id = idx + (size_t)pr * KNN;
    float m = -INFINITY;
    #pragma unroll
    for (int k = 0; k < KNN; k++) {
        int j = id[k];
        float u = U[((size_t)(b * PPTS + j) << lgO) + o];
        m = fmaxf(m, u);
    }
    float val = lrelu((m + V[((size_t)pr << lgO) + o]) * sc[o] + bi[o]);
    xout[(size_t)pr * 512 + o] = val;
    _Float16 hv = (_Float16)val;
    int prg = pr >> 4, prr = pr & 15;
    if (hnext)
        hnext[(size_t)prg * 16 * O + (o >> 5) * 512 + prr * 32 + (o & 31)] = hv;
    xcf[(size_t)prg * 8192 + ((co + o) >> 5) * 512 + prr * 32 + (o & 31)] = hv;
}

// ---------------- fused conv5 + pool (tiled inputs): partial max/sum per (cluster, chunk, o) ----------------
__global__ __launch_bounds__(256, 4) void conv5pool_kernel(
    const _Float16* __restrict__ xcf, const _Float16* __restrict__ w5f,
    const float* __restrict__ s5, const float* __restrict__ b5,
    float* __restrict__ pmax, float* __restrict__ psum)
{
    __shared__ float lmax[4][128], lsum[4][128];
    const int w = threadIdx.x >> 6;
    const int lane = threadIdx.x & 63;
    const int col16 = lane & 15, quad = lane >> 4;
    const int p0 = blockIdx.x * 64 + w * 16;
    const int o0 = blockIdx.y * 128;
    const _Float16* aB = xcf + (size_t)(p0 >> 4) * 8192 + col16 * 32 + quad * 8;
    const _Float16* bB = w5f + (size_t)(o0 >> 4) * 8192 + col16 * 32 + quad * 8;
    f32x4 acc[8] = {};
    #pragma unroll 2
    for (int kc = 0; kc < 16; kc++) {
        f16x8 a = *(const f16x8*)&aB[kc * 512];
        #pragma unroll
        for (int t = 0; t < 8; t++) {
            f16x8 bf = *(const f16x8*)&bB[(size_t)t * 8192 + kc * 512];
            acc[t] = __builtin_amdgcn_mfma_f32_16x16x32_f16(a, bf, acc[t], 0, 0, 0);
        }
    }
    #pragma unroll
    for (int t = 0; t < 8; t++) {
        int o = o0 + t * 16 + col16;
        float sc = s5[o], bi = b5[o];
        float vm = -INFINITY, vs = 0.f;
        #pragma unroll
        for (int r = 0; r < 4; r++) {
            float val = lrelu(acc[t][r] * sc + bi);
            vm = fmaxf(vm, val); vs += val;
        }
        #pragma unroll
        for (int off = 16; off < 64; off <<= 1) {
            vm = fmaxf(vm, __shfl_xor(vm, off));
            vs += __shfl_xor(vs, off);
        }
        if (quad == 0) { lmax[w][t * 16 + col16] = vm; lsum[w][t * 16 + col16] = vs; }
    }
    __syncthreads();
    if (threadIdx.x < 128) {
        int col = threadIdx.x;
        float m = lmax[0][col], s = lsum[0][col];
        #pragma unroll
        for (int q = 1; q < 4; q++) { m = fmaxf(m, lmax[q][col]); s += lsum[q][col]; }
        int cl = blockIdx.x >> 4, chunk = blockIdx.x & 15;
        size_t o = (size_t)(cl * 16 + chunk) * 512 + o0 + col;
        pmax[o] = m; psum[o] = s;
    }
}

// ---------------- pool reduce over 16 chunks ----------------
__global__ void poolred_kernel(const float* __restrict__ pmax, const float* __restrict__ psum,
                               float* __restrict__ feat) {
    int n = blockIdx.x * 256 + threadIdx.x;   // 16*512
    int o = n & 511, cl = n >> 9;
    float m = -INFINITY, s = 0.f;
    #pragma unroll
    for (int c = 0; c < 16; c++) {
        size_t q = (size_t)(cl * 16 + c) * 512 + o;
        m = fmaxf(m, pmax[q]); s += psum[q];
    }
    feat[(size_t)cl * 1024 + o] = m;
    feat[(size_t)cl * 1024 + 512 + o] = s * (1.f / 1024.f);
}

// ---------------- final MLP ----------------
__global__ void mlp1_kernel(const float* __restrict__ feat, const float* __restrict__ L1,
                            const float* __restrict__ s6, const float* __restrict__ b6,
                            float* __restrict__ z1) {
    int n = blockIdx.x * 256 + threadIdx.x;   // 16*512
    int o = n & 511, b = n >> 9;
    const float* f = feat + (size_t)b * 1024;
    const float* w = L1 + (size_t)o * 1024;
    float acc = 0.f;
    for (int c = 0; c < 1024; c++) acc = fmaf(f[c], w[c], acc);
    z1[n] = lrelu(acc * s6[o] + b6[o]);
}

__global__ void mlp2_kernel(const float* __restrict__ z1, const float* __restrict__ L2,
                            const float* __restrict__ bl2,
                            const float* __restrict__ s7, const float* __restrict__ b7,
                            float* __restrict__ z2) {
    int n = blockIdx.x * 256 + threadIdx.x;   // 16*256
    int o = n & 255, b = n >> 8;
    const float* f = z1 + (size_t)b * 512;
    const float* w = L2 + (size_t)o * 512;
    float acc = 0.f;
    for (int c = 0; c < 512; c++) acc = fmaf(f[c], w[c], acc);
    z2[n] = lrelu((acc + bl2[o]) * s7[o] + b7[o]);
}

__global__ void mlp3_kernel(const float* __restrict__ z2, const float* __restrict__ L3,
                            const float* __restrict__ bl3, float* __restrict__ out) {
    __shared__ float red[256];
    int t = threadIdx.x;
    int b = t >> 4, q = t & 15;
    float acc = 0.f;
    for (int c = q * 16; c < q * 16 + 16; c++) acc = fmaf(z2[(size_t)b * 256 + c], L3[c], acc);
    red[t] = acc;
    __syncthreads();
    if (q == 0) {
        float s = 0.f;
        #pragma unroll
        for (int i = 0; i < 16; i++) s += red[b * 16 + i];
        s += bl3[0];
        out[b] = 1.f / (1.f + expf(-s));
    }
}

extern "C" void kernel_launch(void* const* d_in, const int* in_sizes, int n_in,
                              void* d_out, int out_size, void* d_ws, size_t ws_size,
                              hipStream_t stream) {
    const float* features = (const float*)d_in[0];
    const int*   clusters = (const int*)d_in[1];
    const float* W1 = (const float*)d_in[2];
    const float* s1 = (const float*)d_in[3];
    const float* b1 = (const float*)d_in[4];
    const float* W2 = (const float*)d_in[5];
    const float* s2 = (const float*)d_in[6];
    const float* b2 = (const float*)d_in[7];
    const float* W3 = (const float*)d_in[8];
    const float* s3 = (const float*)d_in[9];
    const float* b3 = (const float*)d_in[10];
    const float* W4 = (const float*)d_in[11];
    const float* s4 = (const float*)d_in[12];
    const float* b4 = (const float*)d_in[13];
    const float* W5 = (const float*)d_in[14];
    const float* s5 = (const float*)d_in[15];
    const float* b5 = (const float*)d_in[16];
    const float* L1 = (const float*)d_in[17];
    const float* s6 = (const float*)d_in[18];
    const float* b6 = (const float*)d_in[19];
    const float* L2 = (const float*)d_in[20];
    const float* bl2 = (const float*)d_in[21];
    const float* s7 = (const float*)d_in[22];
    const float* b7 = (const float*)d_in[23];
    const float* L3 = (const float*)d_in[24];
    const float* bl3 = (const float*)d_in[25];

    float* ws = (float*)d_ws;
    // workspace layout (float units)
    float* h0  = ws;                                      // 2,097,152
    float* xc  = h0 + 2097152;                            // 8,388,608
    float* U   = xc + 8388608;                            // 4,194,304 (max O=256)
    float* V   = U + 4194304;                             // 4,194,304
    _Float16* xcf16 = (_Float16*)(V + 4194304);           // 8,388,608 halfs (tiled K=512)
    _Float16* w5f16 = xcf16 + 8388608;                    // 262,144 halfs (tiled K=512)
    _Float16* hf16  = w5f16 + 262144;                     // 2,097,152 halfs (tiled, K=C)
    _Float16* wn16  = hf16 + 2097152;                     // 32,768 halfs (tiled K=C)
    _Float16* wv16  = wn16 + 32768;                       // 32,768 halfs
    int*   idx  = (int*)(wv16 + 32768);                   // 327,680 ints
    float* sq   = (float*)(idx + 327680);                 // 16,384
    float* pmax = sq + 16384;                             // 131,072
    float* psum = pmax + 131072;                          // 131,072
    float* feat = psum + 131072;                          // 16,384
    float* z1   = feat + 16384;                           // 8,192
    float* z2   = z1 + 8192;                              // 4,096

    gather_kernel<<<2048, 256, 0, stream>>>((const float4*)features, clusters,
                                            (float4*)h0, (f16x4*)hf16);

    auto stage = [&](const float* hin, int ldh, int C, int O, int lgO,
                     const float* W, const float* sc, const float* bi,
                     float* xout, int co, _Float16* hnext) {
        int lgC4 = (C == 128) ? 5 : 4;
        sq_kernel<<<4096, 256, 0, stream>>>(hin, ldh, C, sq);
        if (C == 128)
            grampk_kernel<128><<<dim3(64, 16), 1024, 0, stream>>>(hf16, sq, idx);
        else
            grampk_kernel<64><<<dim3(64, 16), 1024, 0, stream>>>(hf16, sq, idx);
        wcvt_kernel<<<(O * (C / 4)) / 256, 256, 0, stream>>>(W, lgC4, (f16x4*)wn16, (f16x4*)wv16);
        if (C == 128)
            uv_mfma_kernel<128><<<dim3(O / 64, 256), 256, 0, stream>>>(hf16, O, wn16, wv16, U, V);
        else
            uv_mfma_kernel<64><<<dim3(O / 64, 256), 256, 0, stream>>>(hf16, O, wn16, wv16, U, V);
        agg_kernel<<<(NCL * PPTS * O) / 256, 256, 0, stream>>>(U, V, idx, lgO, sc, bi,
                                                               xout, hnext, xcf16, co);
    };

    stage(h0,       128, 128,  64, 6, W1, s1, b1, xc + 0,   0,   hf16);
    stage(xc + 0,   512,  64,  64, 6, W2, s2, b2, xc + 64,  64,  hf16);
    stage(xc + 64,  512,  64, 128, 7, W3, s3, b3, xc + 128, 128, hf16);
    stage(xc + 128, 512, 128, 256, 8, W4, s4, b4, xc + 256, 256, (_Float16*)nullptr);

    tof16_tiled_kernel<<<256, 256, 0, stream>>>(W5, (f16x4*)w5f16);
    conv5pool_kernel<<<dim3(256, 4), 256, 0, stream>>>(xcf16, w5f16, s5, b5, pmax, psum);
    poolred_kernel<<<32, 256, 0, stream>>>(pmax, psum, feat);
    mlp1_kernel<<<32, 256, 0, stream>>>(feat, L1, s6, b6, z1);
    mlp2_kernel<<<16, 256, 0, stream>>>(z1, L2, bl2, s7, b7, z2);
    mlp3_kernel<<<1, 256, 0, stream>>>(z2, L3, bl3, (float*)d_out);
}

// Round 8
// 465.419 us; speedup vs baseline: 1.6605x; 1.0819x over previous
//
#include <hip/hip_runtime.h>
#include <math.h>

#define KNN 20
#define PPTS 1024
#define NCL 16

typedef _Float16 f16x8 __attribute__((ext_vector_type(8)));
typedef _Float16 f16x4 __attribute__((ext_vector_type(4)));
typedef float f32x4 __attribute__((ext_vector_type(4)));

__device__ __forceinline__ float lrelu(float x) { return x > 0.f ? x : 0.2f * x; }

// DPP max-reduce step (ctrl must be a literal)
#define DPPMAX(x, ctrl) { \
    unsigned _t = (unsigned)__builtin_amdgcn_update_dpp((int)(x), (int)(x), ctrl, 0xF, 0xF, false); \
    (x) = (x) > _t ? (x) : _t; }

// Fragment-tiled f16 layout: 16-row x 32-col tiles, row-major within tile.
// half-index(row, k, K) = (row>>4)*16*K + (k>>5)*512 + (row&15)*32 + (k&31)

// ---------------- gather: hf16 tiled (K=128) + row sq ----------------
__global__ void gather_kernel(const float4* __restrict__ feat,
                              const int* __restrict__ clusters,
                              f16x4* __restrict__ hf,
                              float* __restrict__ sqp) {
    int n = blockIdx.x * 256 + threadIdx.x;   // over NCL*PPTS*32 float4s
    int c4 = n & 31;                           // k = c4*4, K=128
    int row = n >> 5;
    int src = clusters[row];
    float4 v = feat[(size_t)src * 32 + c4];
    f16x4 o;
    o[0] = (_Float16)v.x; o[1] = (_Float16)v.y; o[2] = (_Float16)v.z; o[3] = (_Float16)v.w;
    hf[(size_t)(row >> 4) * 512 + (c4 >> 3) * 128 + (row & 15) * 8 + (c4 & 7)] = o;
    float s = v.x * v.x + v.y * v.y + v.z * v.z + v.w * v.w;
    #pragma unroll
    for (int off = 16; off; off >>= 1) s += __shfl_xor(s, off);   // 32-lane group
    if (c4 == 0) { sqp[2 * row] = s; sqp[2 * row + 1] = 0.f; }
}

// ---------------- W5 f32 row-major -> f16 tiled (K=512) ----------------
__global__ void tof16_tiled_kernel(const float* __restrict__ src,
                                   f16x4* __restrict__ dst) {
    int n = blockIdx.x * 256 + threadIdx.x;    // rows*128 threads
    int c4 = n & 127;
    int row = n >> 7;
    float4 v = *(const float4*)&src[(size_t)row * 512 + c4 * 4];
    f16x4 o;
    o[0] = (_Float16)v.x; o[1] = (_Float16)v.y; o[2] = (_Float16)v.z; o[3] = (_Float16)v.w;
    dst[(size_t)(row >> 4) * 2048 + (c4 >> 3) * 128 + (row & 15) * 8 + (c4 & 7)] = o;
}

// ---------------- weight split+convert (tiled, K=C) ----------------
__global__ void wcvt_kernel(const float* __restrict__ W, int lgC4,
                            f16x4* __restrict__ wn, f16x4* __restrict__ wv) {
    int n = blockIdx.x * 256 + threadIdx.x;   // O * C/4 threads
    int c4 = n & ((1 << lgC4) - 1);
    int o = n >> lgC4;
    int C = 4 << lgC4;
    float4 a = *(const float4*)&W[(size_t)o * 2 * C + c4 * 4];
    float4 b = *(const float4*)&W[(size_t)o * 2 * C + C + c4 * 4];
    f16x4 on, ov;
    on[0] = (_Float16)a.x; on[1] = (_Float16)a.y; on[2] = (_Float16)a.z; on[3] = (_Float16)a.w;
    ov[0] = (_Float16)(b.x - a.x); ov[1] = (_Float16)(b.y - a.y);
    ov[2] = (_Float16)(b.z - a.z); ov[3] = (_Float16)(b.w - a.w);
    size_t ti = (size_t)(o >> 4) * (C * 4) + (c4 >> 3) * 128 + (o & 15) * 8 + (c4 & 7);
    wn[ti] = on; wv[ti] = ov;
}

// ---------------- fused gram + top-K, 1024-thread blocks, tiled hf ----------------
// MFMA phase as R7; extraction: per-lane Batcher sort + DPP argmax + shift-down.
template<int C>
__global__ __launch_bounds__(1024, 8) void grampk_kernel(
    const _Float16* __restrict__ hf,
    const float* __restrict__ sqp, int* __restrict__ idx)
{
    __shared__ unsigned keys[16 * 1024];   // 64 KB
    const int b = blockIdx.y;
    const _Float16* hb = hf + (size_t)b * PPTS * C;
    const float* sqb = sqp + 2 * (b << 10);
    const int w = threadIdx.x >> 6;          // 0..15
    const int lane = threadIdx.x & 63;
    const int col16 = lane & 15, quad = lane >> 4;
    const int i0 = blockIdx.x * 16;
    const int j0 = w * 64;
    const _Float16* aB = hb + (size_t)blockIdx.x * 16 * C + col16 * 32 + quad * 8;
    const _Float16* bB = hb + (size_t)(w * 4) * 16 * C + col16 * 32 + quad * 8;
    f32x4 acc[4] = {};
    #pragma unroll
    for (int kc = 0; kc < C / 32; kc++) {
        f16x8 a = *(const f16x8*)&aB[kc * 512];
        #pragma unroll
        for (int t = 0; t < 4; t++) {
            f16x8 bf = *(const f16x8*)&bB[(size_t)t * 16 * C + kc * 512];
            acc[t] = __builtin_amdgcn_mfma_f32_16x16x32_f16(a, bf, acc[t], 0, 0, 0);
        }
    }
    float sqi[4];
    #pragma unroll
    for (int r = 0; r < 4; r++) {
        int rw = i0 + quad * 4 + r;
        sqi[r] = sqb[2 * rw] + sqb[2 * rw + 1];
    }
    #pragma unroll
    for (int t = 0; t < 4; t++) {
        int j = j0 + t * 16 + col16;
        float sqj = sqb[2 * j] + sqb[2 * j + 1];
        #pragma unroll
        for (int r = 0; r < 4; r++) {
            int row = quad * 4 + r;
            float val = 2.f * acc[t][r] - sqi[r] - sqj;
            unsigned u = __float_as_uint(val);
            unsigned key = (u & 0x80000000u) ? ~u : (u | 0x80000000u);
            keys[(row << 10) | ((j + 2 * row) & 1023)] = (key & 0xFFFFFC00u) | (unsigned)j;
        }
    }
    __syncthreads();
    // extraction: wave w handles row w
    {
        const int row = w;
        unsigned v[16];
        #pragma unroll
        for (int s = 0; s < 16; s++) v[s] = keys[(row << 10) | (s * 64 + lane)];
        // Batcher odd-even mergesort, descending, 63 compare-exchanges
        #pragma unroll
        for (int p = 1; p < 16; p <<= 1)
            #pragma unroll
            for (int k = p; k >= 1; k >>= 1)
                #pragma unroll
                for (int j = k & (p - 1); j + k < 16; j += 2 * k)
                    #pragma unroll
                    for (int i = 0; i < k; i++)
                        if ((i + j + k < 16) && ((i + j) / (2 * p) == (i + j + k) / (2 * p))) {
                            unsigned a = v[i + j], c = v[i + j + k];
                            v[i + j] = a > c ? a : c;
                            v[i + j + k] = a > c ? c : a;
                        }
        unsigned mloc = v[0];
        unsigned myout = 0;
        for (int kk = 0; kk < KNN; kk++) {
            unsigned x = mloc;
            DPPMAX(x, 0xB1);   // quad_perm(1,0,3,2)
            DPPMAX(x, 0x4E);   // quad_perm(2,3,0,1)
            DPPMAX(x, 0x141);  // row_half_mirror -> 8
            DPPMAX(x, 0x140);  // row_mirror -> 16
            DPPMAX(x, 0x142);  // row_bcast15 -> 32
            DPPMAX(x, 0x143);  // row_bcast31 -> 64 @ lane63
            unsigned gm = (unsigned)__builtin_amdgcn_readlane((int)x, 63);
            if (lane == kk) myout = gm & 1023u;
            bool wl = (mloc == gm);          // unique: key carries index bits
            #pragma unroll
            for (int s = 0; s < 15; s++) v[s] = wl ? v[s + 1] : v[s];
            v[15] = wl ? 0u : v[15];
            mloc = v[0];
        }
        if (lane < KNN) idx[((size_t)b * PPTS + i0 + row) * KNN + lane] = (int)myout;
    }
}

// ---------------- U/V via f16 MFMA, tiled inputs ----------------
template<int C>
__global__ __launch_bounds__(256, 4) void uv_mfma_kernel(
    const _Float16* __restrict__ hf, int O,
    const _Float16* __restrict__ wn, const _Float16* __restrict__ wv,
    float* __restrict__ U, float* __restrict__ V)
{
    const int w = threadIdx.x >> 6;
    const int lane = threadIdx.x & 63;
    const int col16 = lane & 15, quad = lane >> 4;
    const int r0 = blockIdx.y * 64 + w * 16;
    const int o0 = blockIdx.x * 64;
    const _Float16* aB = hf + (size_t)(r0 >> 4) * 16 * C + col16 * 32 + quad * 8;
    const _Float16* nB = wn + (size_t)(o0 >> 4) * 16 * C + col16 * 32 + quad * 8;
    const _Float16* vB = wv + (size_t)(o0 >> 4) * 16 * C + col16 * 32 + quad * 8;
    f32x4 au[4] = {}, av[4] = {};
    #pragma unroll
    for (int kc = 0; kc < C / 32; kc++) {
        f16x8 a = *(const f16x8*)&aB[kc * 512];
        #pragma unroll
        for (int t = 0; t < 4; t++) {
            f16x8 bn = *(const f16x8*)&nB[(size_t)t * 16 * C + kc * 512];
            au[t] = __builtin_amdgcn_mfma_f32_16x16x32_f16(a, bn, au[t], 0, 0, 0);
            f16x8 bv = *(const f16x8*)&vB[(size_t)t * 16 * C + kc * 512];
            av[t] = __builtin_amdgcn_mfma_f32_16x16x32_f16(a, bv, av[t], 0, 0, 0);
        }
    }
    #pragma unroll
    for (int t = 0; t < 4; t++) {
        int o = o0 + t * 16 + col16;
        #pragma unroll
        for (int r = 0; r < 4; r++) {
            int p = r0 + quad * 4 + r;
            U[(size_t)p * O + o] = au[t][r];
            V[(size_t)p * O + o] = av[t][r];
        }
    }
}

// ---------------- aggregate: lrelu(s*(max_k U[idx] + V) + b) -> tiled f16; fused next-stage sq ----------------
__global__ void agg_kernel(const float* __restrict__ U, const float* __restrict__ V,
                           const int* __restrict__ idx, int lgO,
                           const float* __restrict__ sc, const float* __restrict__ bi,
                           _Float16* __restrict__ hnext,        // tiled [rows][O], may be null
                           _Float16* __restrict__ xcf, int co,  // tiled [rows][512], col offset
                           float* __restrict__ sqp)
{
    int n = blockIdx.x * 256 + threadIdx.x;
    int O = 1 << lgO;
    int o = n & (O - 1);
    int pr = n >> lgO;           // b*P+p
    int b = pr >> 10;
    const int* id = idx + (size_t)pr * KNN;
    float m = -INFINITY;
    #pragma unroll
    for (int k = 0; k < KNN; k++) {
        int j = id[k];
        float u = U[((size_t)(b * PPTS + j) << lgO) + o];
        m = fmaxf(m, u);
    }
    float val = lrelu((m + V[((size_t)pr << lgO) + o]) * sc[o] + bi[o]);
    _Float16 hv = (_Float16)val;
    int prg = pr >> 4, prr = pr & 15;
    xcf[(size_t)prg * 8192 + ((co + o) >> 5) * 512 + prr * 32 + (o & 31)] = hv;
    if (hnext) {
        hnext[(size_t)prg * 16 * O + (o >> 5) * 512 + prr * 32 + (o & 31)] = hv;
        float s = val * val;
        #pragma unroll
        for (int off = 32; off; off >>= 1) s += __shfl_xor(s, off);   // wave = 64 o's of this pr
        if ((threadIdx.x & 63) == 0) {
            sqp[2 * pr + ((o >> 6) & 1)] = s;
            if (lgO == 6) sqp[2 * pr + 1] = 0.f;
        }
    }
}

// ---------------- fused conv5 + pool (tiled inputs) ----------------
__global__ __launch_bounds__(256, 4) void conv5pool_kernel(
    const _Float16* __restrict__ xcf, const _Float16* __restrict__ w5f,
    const float* __restrict__ s5, const float* __restrict__ b5,
    float* __restrict__ pmax, float* __restrict__ psum)
{
    __shared__ float lmax[4][128], lsum[4][128];
    const int w = threadIdx.x >> 6;
    const int lane = threadIdx.x & 63;
    const int col16 = lane & 15, quad = lane >> 4;
    const int p0 = blockIdx.x * 64 + w * 16;
    const int o0 = blockIdx.y * 128;
    const _Float16* aB = xcf + (size_t)(p0 >> 4) * 8192 + col16 * 32 + quad * 8;
    const _Float16* bB = w5f + (size_t)(o0 >> 4) * 8192 + col16 * 32 + quad * 8;
    f32x4 acc[8] = {};
    #pragma unroll 2
    for (int kc = 0; kc < 16; kc++) {
        f16x8 a = *(const f16x8*)&aB[kc * 512];
        #pragma unroll
        for (int t = 0; t < 8; t++) {
            f16x8 bf = *(const f16x8*)&bB[(size_t)t * 8192 + kc * 512];
            acc[t] = __builtin_amdgcn_mfma_f32_16x16x32_f16(a, bf, acc[t], 0, 0, 0);
        }
    }
    #pragma unroll
    for (int t = 0; t < 8; t++) {
        int o = o0 + t * 16 + col16;
        float sc = s5[o], bi = b5[o];
        float vm = -INFINITY, vs = 0.f;
        #pragma unroll
        for (int r = 0; r < 4; r++) {
            float val = lrelu(acc[t][r] * sc + bi);
            vm = fmaxf(vm, val); vs += val;
        }
        #pragma unroll
        for (int off = 16; off < 64; off <<= 1) {
            vm = fmaxf(vm, __shfl_xor(vm, off));
            vs += __shfl_xor(vs, off);
        }
        if (quad == 0) { lmax[w][t * 16 + col16] = vm; lsum[w][t * 16 + col16] = vs; }
    }
    __syncthreads();
    if (threadIdx.x < 128) {
        int col = threadIdx.x;
        float m = lmax[0][col], s = lsum[0][col];
        #pragma unroll
        for (int q = 1; q < 4; q++) { m = fmaxf(m, lmax[q][col]); s += lsum[q][col]; }
        int cl = blockIdx.x >> 4, chunk = blockIdx.x & 15;
        size_t o = (size_t)(cl * 16 + chunk) * 512 + o0 + col;
        pmax[o] = m; psum[o] = s;
    }
}

// ---------------- pool reduce over 16 chunks ----------------
__global__ void poolred_kernel(const float* __restrict__ pmax, const float* __restrict__ psum,
                               float* __restrict__ feat) {
    int n = blockIdx.x * 256 + threadIdx.x;   // 16*512
    int o = n & 511, cl = n >> 9;
    float m = -INFINITY, s = 0.f;
    #pragma unroll
    for (int c = 0; c < 16; c++) {
        size_t q = (size_t)(cl * 16 + c) * 512 + o;
        m = fmaxf(m, pmax[q]); s += psum[q];
    }
    feat[(size_t)cl * 1024 + o] = m;
    feat[(size_t)cl * 1024 + 512 + o] = s * (1.f / 1024.f);
}

// ---------------- final MLP ----------------
__global__ void mlp1_kernel(const float* __restrict__ feat, const float* __restrict__ L1,
                            const float* __restrict__ s6, const float* __restrict__ b6,
                            float* __restrict__ z1) {
    int n = blockIdx.x * 256 + threadIdx.x;   // 16*512
    int o = n & 511, b = n >> 9;
    const float* f = feat + (size_t)b * 1024;
    const float* w = L1 + (size_t)o * 1024;
    float acc = 0.f;
    for (int c = 0; c < 1024; c++) acc = fmaf(f[c], w[c], acc);
    z1[n] = lrelu(acc * s6[o] + b6[o]);
}

__global__ void mlp2_kernel(const float* __restrict__ z1, const float* __restrict__ L2,
                            const float* __restrict__ bl2,
                            const float* __restrict__ s7, const float* __restrict__ b7,
                            float* __restrict__ z2) {
    int n = blockIdx.x * 256 + threadIdx.x;   // 16*256
    int o = n & 255, b = n >> 8;
    const float* f = z1 + (size_t)b * 512;
    const float* w = L2 + (size_t)o * 512;
    float acc = 0.f;
    for (int c = 0; c < 512; c++) acc = fmaf(f[c], w[c], acc);
    z2[n] = lrelu((acc + bl2[o]) * s7[o] + b7[o]);
}

__global__ void mlp3_kernel(const float* __restrict__ z2, const float* __restrict__ L3,
                            const float* __restrict__ bl3, float* __restrict__ out) {
    __shared__ float red[256];
    int t = threadIdx.x;
    int b = t >> 4, q = t & 15;
    float acc = 0.f;
    for (int c = q * 16; c < q * 16 + 16; c++) acc = fmaf(z2[(size_t)b * 256 + c], L3[c], acc);
    red[t] = acc;
    __syncthreads();
    if (q == 0) {
        float s = 0.f;
        #pragma unroll
        for (int i = 0; i < 16; i++) s += red[b * 16 + i];
        s += bl3[0];
        out[b] = 1.f / (1.f + expf(-s));
    }
}

extern "C" void kernel_launch(void* const* d_in, const int* in_sizes, int n_in,
                              void* d_out, int out_size, void* d_ws, size_t ws_size,
                              hipStream_t stream) {
    const float* features = (const float*)d_in[0];
    const int*   clusters = (const int*)d_in[1];
    const float* W1 = (const float*)d_in[2];
    const float* s1 = (const float*)d_in[3];
    const float* b1 = (const float*)d_in[4];
    const float* W2 = (const float*)d_in[5];
    const float* s2 = (const float*)d_in[6];
    const float* b2 = (const float*)d_in[7];
    const float* W3 = (const float*)d_in[8];
    const float* s3 = (const float*)d_in[9];
    const float* b3 = (const float*)d_in[10];
    const float* W4 = (const float*)d_in[11];
    const float* s4 = (const float*)d_in[12];
    const float* b4 = (const float*)d_in[13];
    const float* W5 = (const float*)d_in[14];
    const float* s5 = (const float*)d_in[15];
    const float* b5 = (const float*)d_in[16];
    const float* L1 = (const float*)d_in[17];
    const float* s6 = (const float*)d_in[18];
    const float* b6 = (const float*)d_in[19];
    const float* L2 = (const float*)d_in[20];
    const float* bl2 = (const float*)d_in[21];
    const float* s7 = (const float*)d_in[22];
    const float* b7 = (const float*)d_in[23];
    const float* L3 = (const float*)d_in[24];
    const float* bl3 = (const float*)d_in[25];

    float* ws = (float*)d_ws;
    float* U   = ws;                                      // 4,194,304 (max O=256)
    float* V   = U + 4194304;                             // 4,194,304
    _Float16* xcf16 = (_Float16*)(V + 4194304);           // 8,388,608 halfs (tiled K=512)
    _Float16* w5f16 = xcf16 + 8388608;                    // 262,144 halfs (tiled K=512)
    _Float16* hf16  = w5f16 + 262144;                     // 2,097,152 halfs (tiled, K=C)
    _Float16* wn16  = hf16 + 2097152;                     // 32,768 halfs
    _Float16* wv16  = wn16 + 32768;                       // 32,768 halfs
    int*   idx  = (int*)(wv16 + 32768);                   // 327,680 ints
    float* sqp  = (float*)(idx + 327680);                 // 32,768 (2 partials/row)
    float* pmax = sqp + 32768;                            // 131,072
    float* psum = pmax + 131072;                          // 131,072
    float* feat = psum + 131072;                          // 16,384
    float* z1   = feat + 16384;                           // 8,192
    float* z2   = z1 + 8192;                              // 4,096

    gather_kernel<<<2048, 256, 0, stream>>>((const float4*)features, clusters,
                                            (f16x4*)hf16, sqp);

    auto stage = [&](int C, int O, int lgO,
                     const float* W, const float* sc, const float* bi,
                     int co, _Float16* hnext) {
        int lgC4 = (C == 128) ? 5 : 4;
        if (C == 128)
            grampk_kernel<128><<<dim3(64, 16), 1024, 0, stream>>>(hf16, sqp, idx);
        else
            grampk_kernel<64><<<dim3(64, 16), 1024, 0, stream>>>(hf16, sqp, idx);
        wcvt_kernel<<<(O * (C / 4)) / 256, 256, 0, stream>>>(W, lgC4, (f16x4*)wn16, (f16x4*)wv16);
        if (C == 128)
            uv_mfma_kernel<128><<<dim3(O / 64, 256), 256, 0, stream>>>(hf16, O, wn16, wv16, U, V);
        else
            uv_mfma_kernel<64><<<dim3(O / 64, 256), 256, 0, stream>>>(hf16, O, wn16, wv16, U, V);
        agg_kernel<<<(NCL * PPTS * O) / 256, 256, 0, stream>>>(U, V, idx, lgO, sc, bi,
                                                               hnext, xcf16, co, sqp);
    };

    stage(128,  64, 6, W1, s1, b1, 0,   hf16);
    stage( 64,  64, 6, W2, s2, b2, 64,  hf16);
    stage( 64, 128, 7, W3, s3, b3, 128, hf16);
    stage(128, 256, 8, W4, s4, b4, 256, (_Float16*)nullptr);

    tof16_tiled_kernel<<<256, 256, 0, stream>>>(W5, (f16x4*)w5f16);
    conv5pool_kernel<<<dim3(256, 4), 256, 0, stream>>>(xcf16, w5f16, s5, b5, pmax, psum);
    poolred_kernel<<<32, 256, 0, stream>>>(pmax, psum, feat);
    mlp1_kernel<<<32, 256, 0, stream>>>(feat, L1, s6, b6, z1);
    mlp2_kernel<<<16, 256, 0, stream>>>(z1, L2, bl2, s7, b7, z2);
    mlp3_kernel<<<1, 256, 0, stream>>>(z2, L3, bl3, (float*)d_out);
}